// Round 1
// baseline (531.785 us; speedup 1.0000x reference)
//
#include <hip/hip_runtime.h>
#include <hip/hip_cooperative_groups.h>
#include <math.h>

namespace cg = cooperative_groups;

#define NB 32
#define CB 256
#define HB 56
#define WB 56
#define PLANE 3136           // floats per (n,c) plane
#define PLANE4 784           // float4 per plane
#define CL 56
#define POOLSZ (NB*CB*CL)
#define YN 1792              // y floats per n: [br][m][l]
#define NCHUNK 1024          // 8-plane chunks total
#define NUM_CU 256

struct KParams {
    const float *x, *w1, *b1, *gamma, *beta, *rmean, *rvar;
    const float *wh, *bh, *ww, *bw, *gw1, *gw2, *gb2, *cw1, *cw2, *cb2;
    float *ph, *pw, *mh, *mw, *gap, *ybuf, *gbuf, *tvec, *sbuf, *out;
};

__device__ inline float wave_sum(float v) {
    #pragma unroll
    for (int o = 32; o; o >>= 1) v += __shfl_xor(v, o, 64);
    return v;
}

// Build per-channel coefficient tables for the 8 channels of chunk (qn,qc0).
// Layout in smem: yb[1792] | cH0[448] cW0[448] cH1[448] cW1[448] | hid[64] sS[8] part[32]
// First __syncthreads also guards table writes against the previous chunk's readers.
__device__ inline void build_tables(const KParams& P, int qn, int qc0, int q0, int t,
        float* yb, float* cH0, float* cW0, float* cH1, float* cW1,
        float* sSm, bool loadS) {
    for (int i = t; i < YN; i += 256) yb[i] = P.ybuf[(size_t)qn * YN + i];
    __syncthreads();
    const float g0 = P.gbuf[qn * 2], g1 = P.gbuf[qn * 2 + 1];
    for (int task = t; task < 448; task += 256) {
        int ci = task / 56, l = task - ci * 56;
        int c = qc0 + ci;
        float h0 = P.bh[c], w0 = P.bw[c], h1 = h0, w1v = w0;
        #pragma unroll
        for (int m = 0; m < 8; ++m) {
            float whv = P.wh[c * 8 + m], wwv = P.ww[c * 8 + m];
            h0  += yb[m * 112 + l]            * whv;
            w0  += yb[m * 112 + 56 + l]       * wwv;
            h1  += yb[896 + m * 112 + l]      * whv;
            w1v += yb[896 + m * 112 + 56 + l] * wwv;
        }
        cH0[task] = 1.f / (1.f + __expf(-h0));
        cW0[task] = g0  / (1.f + __expf(-w0));
        cH1[task] = 1.f / (1.f + __expf(-h1));
        cW1[task] = g1  / (1.f + __expf(-w1v));
    }
    if (loadS && t < 8) sSm[t] = P.sbuf[q0 + t];
    __syncthreads();
}

__global__ __launch_bounds__(256, 4) void k_fused(KParams P) {
    cg::grid_group grid = cg::this_grid();
    __shared__ float smem[6384];             // 25.5 KB -> 4 blocks/CU fits easily
    const int t   = threadIdx.x;
    const int bid = blockIdx.x;
    const int G   = gridDim.x;
    const int wv  = t >> 6, ln = t & 63;

    // ---------------- Phase 1: pooling (8 planes/chunk, 2 planes per round) -----
    for (int g = bid; g < NCHUNK; g += G) {
        const int q0 = g * 8;
        for (int r = 0; r < 4; ++r) {
            const int pA = q0 + 2 * r;
            const float4* x4 = (const float4*)(P.x + (size_t)pA * PLANE);
            for (int j = t; j < 2 * PLANE4; j += 256) {
                float4 v = x4[j];
                int pl = j / PLANE4, jj = j - pl * PLANE4;
                int h = jj / 14, wq = jj - h * 14;
                float* d = &smem[pl * 3192 + h * 57 + wq * 4];
                d[0] = v.x; d[1] = v.y; d[2] = v.z; d[3] = v.w;
            }
            __syncthreads();
            const int pl = wv >> 1;                  // waves 0,1 -> plane A; 2,3 -> B
            const float* tb = &smem[pl * 3192];
            const size_t pidx = (size_t)(pA + pl) * CL;
            if (!(wv & 1)) {                         // even wave: column scans
                if (ln < CL) {
                    float s = 0.f, m = -INFINITY;
                    #pragma unroll 8
                    for (int h = 0; h < HB; ++h) { float v = tb[h * 57 + ln]; s += v; m = fmaxf(m, v); }
                    P.pw[pidx + ln] = s * (1.f / HB);
                    P.mw[pidx + ln] = m;
                }
            } else {                                 // odd wave: row scans + gap
                float s = 0.f, m = -INFINITY;
                if (ln < CL) {
                    #pragma unroll 8
                    for (int wq = 0; wq < WB; ++wq) { float v = tb[ln * 57 + wq]; s += v; m = fmaxf(m, v); }
                    P.ph[pidx + ln] = s * (1.f / WB);
                    P.mh[pidx + ln] = m;
                }
                float tot = wave_sum(s);             // lanes >=56 contribute 0
                if (ln == 0) P.gap[pA + pl] = tot * (1.f / PLANE);
            }
            __syncthreads();
        }
    }
    grid.sync();

    // ---------------- Phase 2: branch y (256 tasks) + gate g (32 tasks) ---------
    for (int g = bid; g < 288; g += G) {
        if (g < 256) {
            const int bn = g >> 3, rem = g & 7, br = rem >> 2, lq = rem & 3;
            const float* pool = br ? ((lq < 2) ? P.mh : P.mw)
                                   : ((lq < 2) ? P.ph : P.pw);
            const int colbase = (lq & 1) * 28;
            float* chunk = smem;                     // [32][29]
            float* lw1s  = smem + 928;               // [8][32]
            const int m = t / 28, li = t - (t / 28) * 28;   // t<224 valid
            float acc = 0.f;
            for (int cc = 0; cc < CB; cc += 32) {
                if (t < 224) {
                    int ci = t / 7, f = t - (t / 7) * 7;
                    const float4* src = (const float4*)(pool + (size_t)(bn * CB + cc + ci) * CL + colbase);
                    float4 v = src[f];
                    float* d = &chunk[ci * 29 + f * 4];
                    d[0] = v.x; d[1] = v.y; d[2] = v.z; d[3] = v.w;
                }
                lw1s[t] = P.w1[(t >> 5) * CB + cc + (t & 31)];
                __syncthreads();
                if (t < 224) {
                    #pragma unroll 8
                    for (int ci = 0; ci < 32; ++ci)
                        acc += chunk[ci * 29 + li] * lw1s[m * 32 + ci];
                }
                __syncthreads();
            }
            if (t < 224) {
                float scale = P.gamma[m] * rsqrtf(P.rvar[m] + 1e-5f);
                float val = (acc + P.b1[m] - P.rmean[m]) * scale + P.beta[m];
                P.ybuf[(size_t)(bn * 2 + br) * 896 + m * 112 + lq * 28 + li] = fmaxf(val, 0.f);
            }
            __syncthreads();
        } else {
            const int gn = g - 256;
            float* hid = smem;
            if (t < 64) {
                float acc = 0.f;
                #pragma unroll 8
                for (int c = 0; c < CB; ++c) acc += P.gap[gn * CB + c] * P.gw1[t * CB + c];
                hid[t] = fmaxf(acc, 0.f);
            }
            __syncthreads();
            if (t == 0) {
                float l0 = P.gb2[0], l1 = P.gb2[1];
                for (int j = 0; j < 64; ++j) { l0 += hid[j] * P.gw2[j]; l1 += hid[j] * P.gw2[64 + j]; }
                float mx = fmaxf(l0, l1);
                float e0 = __expf(l0 - mx), e1 = __expf(l1 - mx);
                float inv = 1.f / (e0 + e1);
                P.gbuf[gn * 2]     = e0 * inv;
                P.gbuf[gn * 2 + 1] = e1 * inv;
            }
            __syncthreads();
        }
    }
    grid.sync();

    // ---------------- Phase 3: coeff tables + tvec ------------------------------
    float* yb   = smem;                      // [1792]
    float* cH0  = smem + 1792;               // [8*56] each
    float* cW0  = cH0 + 448;
    float* cH1  = cW0 + 448;
    float* cW1  = cH1 + 448;
    float* hid  = smem + 3584;               // [64]
    float* sSm  = smem + 3648;               // [8]
    float* part = smem + 3656;               // [8][4]

    for (int g = bid; g < NCHUNK; g += G) {
        const int q0 = g * 8, qn = q0 >> 8, qc0 = q0 & 255;
        build_tables(P, qn, qc0, q0, t, yb, cH0, cW0, cH1, cW1, sSm, false);
        #pragma unroll 1
        for (int i = 0; i < 8; ++i) {
            const float4* xp4 = (const float4*)(P.x + (size_t)(q0 + i) * PLANE);
            const float4* a4 = (const float4*)(cW0 + i * 56);
            const float4* b4 = (const float4*)(cW1 + i * 56);
            const float* h0p = cH0 + i * 56;
            const float* h1p = cH1 + i * 56;
            float acc = 0.f;
            for (int j = t; j < PLANE4; j += 256) {
                float4 v = xp4[j];
                int h = j / 14, wq = j - h * 14;
                float h0 = h0p[h], h1 = h1p[h];
                float4 a = a4[wq], b = b4[wq];
                acc += v.x * (h0 * a.x + h1 * b.x) + v.y * (h0 * a.y + h1 * b.y)
                     + v.z * (h0 * a.z + h1 * b.z) + v.w * (h0 * a.w + h1 * b.w);
            }
            float s = wave_sum(acc);
            if (ln == 0) part[i * 4 + wv] = s;
        }
        __syncthreads();
        if (t < 8)
            P.tvec[q0 + t] = (part[t * 4] + part[t * 4 + 1] + part[t * 4 + 2] + part[t * 4 + 3]) * (1.f / PLANE);
    }
    grid.sync();

    // ---------------- Phase 3.5: s-gate (32 tasks) ------------------------------
    for (int g = bid; g < NB; g += G) {
        float* tv = smem;                    // reuse yb region
        tv[t] = P.tvec[g * CB + t];
        __syncthreads();
        if (t < 64) {
            float acc = 0.f;
            #pragma unroll 8
            for (int c = 0; c < CB; ++c) acc += tv[c] * P.cw1[t * CB + c];
            hid[t] = fmaxf(acc, 0.f);
        }
        __syncthreads();
        float acc = P.cb2[t];
        #pragma unroll 8
        for (int j = 0; j < 64; ++j) acc += hid[j] * P.cw2[t * 64 + j];
        P.sbuf[g * CB + t] = 1.f / (1.f + __expf(-acc));
        __syncthreads();
    }
    grid.sync();

    // ---------------- Phase 4: final output -------------------------------------
    for (int g = bid; g < NCHUNK; g += G) {
        const int q0 = g * 8, qn = q0 >> 8, qc0 = q0 & 255;
        build_tables(P, qn, qc0, q0, t, yb, cH0, cW0, cH1, cW1, sSm, true);
        #pragma unroll 1
        for (int i = 0; i < 8; ++i) {
            const float sv = sSm[i];
            const float4* xp4 = (const float4*)(P.x + (size_t)(q0 + i) * PLANE);
            float4* op4 = (float4*)(P.out + (size_t)(q0 + i) * PLANE);
            const float4* a4 = (const float4*)(cW0 + i * 56);
            const float4* b4 = (const float4*)(cW1 + i * 56);
            const float* h0p = cH0 + i * 56;
            const float* h1p = cH1 + i * 56;
            for (int j = t; j < PLANE4; j += 256) {
                float4 v = xp4[j];
                int h = j / 14, wq = j - h * 14;
                float h0 = h0p[h] * sv, h1 = h1p[h] * sv;
                float4 a = a4[wq], b = b4[wq];
                float4 rr;
                rr.x = v.x * (h0 * a.x + h1 * b.x + 1.f);
                rr.y = v.y * (h0 * a.y + h1 * b.y + 1.f);
                rr.z = v.z * (h0 * a.z + h1 * b.z + 1.f);
                rr.w = v.w * (h0 * a.w + h1 * b.w + 1.f);
                op4[j] = rr;
            }
        }
    }
}

// =========================== Fallback path (verified 4-kernel) ==================

__global__ __launch_bounds__(256) void k_pool(const float* __restrict__ x,
        float* __restrict__ ph, float* __restrict__ pw,
        float* __restrict__ mh, float* __restrict__ mw, float* __restrict__ gap) {
    int t = threadIdx.x;
    __shared__ float tile[HB * 57];
    for (int i = 0; i < 4; ++i) {
        int p = blockIdx.x * 4 + i;
        const float4* xp4 = (const float4*)(x + (size_t)p * PLANE);
        for (int j = t; j < PLANE4; j += 256) {
            float4 v = xp4[j];
            int h = j / 14, w4 = (j - h * 14) * 4;
            float* d = &tile[h * 57 + w4];
            d[0] = v.x; d[1] = v.y; d[2] = v.z; d[3] = v.w;
        }
        __syncthreads();
        if (t < CL) {
            float csum = 0.f, cmax = -INFINITY;
            #pragma unroll 8
            for (int h = 0; h < HB; ++h) {
                float v = tile[h * 57 + t];
                csum += v; cmax = fmaxf(cmax, v);
            }
            size_t idx = (size_t)p * CL + t;
            pw[idx] = csum * (1.f / HB);
            mw[idx] = cmax;
        } else if (t >= 64 && t < 128) {
            int r = t - 64;
            float rsum = 0.f, rmax = -INFINITY;
            if (r < CL) {
                #pragma unroll 8
                for (int w = 0; w < WB; ++w) {
                    float v = tile[r * 57 + w];
                    rsum += v; rmax = fmaxf(rmax, v);
                }
                size_t idx = (size_t)p * CL + r;
                ph[idx] = rsum * (1.f / WB);
                mh[idx] = rmax;
            }
            float tot = wave_sum(rsum);
            if (r == 0) gap[p] = tot * (1.f / PLANE);
        }
        __syncthreads();
    }
}

__global__ __launch_bounds__(256) void k_branch(
        const float* __restrict__ ph, const float* __restrict__ pw,
        const float* __restrict__ mh, const float* __restrict__ mw,
        const float* __restrict__ gap,
        const float* __restrict__ w1, const float* __restrict__ b1,
        const float* __restrict__ gamma, const float* __restrict__ beta,
        const float* __restrict__ rmean, const float* __restrict__ rvar,
        const float* __restrict__ gw1, const float* __restrict__ gw2,
        const float* __restrict__ gb2,
        float* __restrict__ yout, float* __restrict__ g) {
    int n = blockIdx.x;
    int br = blockIdx.y;
    const float* pool_h = br ? mh : ph;
    const float* pool_w = br ? mw : pw;
    __shared__ float tile[CB * 113];
    __shared__ float lw1[8 * CB];
    __shared__ float hid[64];
    int t = threadIdx.x;

    for (int i = t; i < 8 * CB; i += 256) lw1[i] = w1[i];
    const float4* ph4 = (const float4*)(pool_h + (size_t)n * (CB * CL));
    const float4* pw4 = (const float4*)(pool_w + (size_t)n * (CB * CL));
    for (int j = t; j < 3584; j += 256) {
        int c = j / 14, w4 = (j - c * 14) * 4;
        float4 v = ph4[j];
        float* d = &tile[c * 113 + w4];
        d[0] = v.x; d[1] = v.y; d[2] = v.z; d[3] = v.w;
        v = pw4[j];
        d = &tile[c * 113 + 56 + w4];
        d[0] = v.x; d[1] = v.y; d[2] = v.z; d[3] = v.w;
    }
    __syncthreads();

    int grp = t / 112, l = t - grp * 112;
    if (grp < 2) {
        int m0 = grp * 4;
        float a0 = 0.f, a1 = 0.f, a2 = 0.f, a3 = 0.f;
        #pragma unroll 8
        for (int c = 0; c < CB; ++c) {
            float v = tile[c * 113 + l];
            a0 += v * lw1[(m0 + 0) * CB + c];
            a1 += v * lw1[(m0 + 1) * CB + c];
            a2 += v * lw1[(m0 + 2) * CB + c];
            a3 += v * lw1[(m0 + 3) * CB + c];
        }
        float acc[4] = {a0, a1, a2, a3};
        #pragma unroll
        for (int k = 0; k < 4; ++k) {
            int m = m0 + k;
            float scale = gamma[m] * rsqrtf(rvar[m] + 1e-5f);
            float val = (acc[k] + b1[m] - rmean[m]) * scale + beta[m];
            yout[(size_t)(n * 2 + br) * 896 + m * 112 + l] = fmaxf(val, 0.f);
        }
    }

    if (br == 0) {
        if (t >= 128 && t < 192) {
            int j = t - 128;
            float acc = 0.f;
            for (int c = 0; c < CB; ++c) acc += gap[n * CB + c] * gw1[j * CB + c];
            hid[j] = fmaxf(acc, 0.f);
        }
        __syncthreads();
        if (t == 0) {
            float l0 = gb2[0], l1 = gb2[1];
            for (int j = 0; j < 64; ++j) { l0 += hid[j] * gw2[j]; l1 += hid[j] * gw2[64 + j]; }
            float mx = fmaxf(l0, l1);
            float e0 = __expf(l0 - mx), e1 = __expf(l1 - mx);
            float inv = 1.f / (e0 + e1);
            g[n * 2]     = e0 * inv;
            g[n * 2 + 1] = e1 * inv;
        }
    }
}

__device__ inline void build_coeffs_old(const float* __restrict__ ybuf,
        const float* __restrict__ wh, const float* __restrict__ bh,
        const float* __restrict__ ww, const float* __restrict__ bw,
        float g0, float g1, int c0, int t,
        float (*cH0)[CL], float (*cW0)[CL], float (*cH1)[CL], float (*cW1)[CL]) {
    if (t < 224) {
        int ci = t / CL, l = t - ci * CL;
        int c = c0 + ci;
        float whv[8], wwv[8];
        #pragma unroll
        for (int m = 0; m < 8; ++m) { whv[m] = wh[c * 8 + m]; wwv[m] = ww[c * 8 + m]; }
        float h0 = bh[c], w0 = bw[c], h1 = bh[c], w1v = bw[c];
        #pragma unroll
        for (int m = 0; m < 8; ++m) {
            h0  += ybuf[m * 112 + l]        * whv[m];
            w0  += ybuf[m * 112 + 56 + l]   * wwv[m];
            h1  += ybuf[896 + m * 112 + l]      * whv[m];
            w1v += ybuf[896 + m * 112 + 56 + l] * wwv[m];
        }
        cH0[ci][l] = 1.f / (1.f + __expf(-h0));
        cW0[ci][l] = g0 / (1.f + __expf(-w0));
        cH1[ci][l] = 1.f / (1.f + __expf(-h1));
        cW1[ci][l] = g1 / (1.f + __expf(-w1v));
    }
}

__global__ __launch_bounds__(256) void k_tsum(const float* __restrict__ x,
        const float* __restrict__ y, const float* __restrict__ g,
        const float* __restrict__ wh, const float* __restrict__ bh,
        const float* __restrict__ ww, const float* __restrict__ bw,
        float* __restrict__ tvec) {
    int t = threadIdx.x;
    int p0 = blockIdx.x * 4;
    int n = p0 >> 8, c0 = p0 & 255;
    __shared__ float ybuf[YN];
    __shared__ float cH0[4][CL], cW0[4][CL], cH1[4][CL], cW1[4][CL];
    __shared__ float part[4][4];
    for (int i = t; i < YN; i += 256) ybuf[i] = y[(size_t)n * YN + i];
    __syncthreads();
    build_coeffs_old(ybuf, wh, bh, ww, bw, g[n * 2], g[n * 2 + 1], c0, t, cH0, cW0, cH1, cW1);
    __syncthreads();
    float acc[4] = {0.f, 0.f, 0.f, 0.f};
    #pragma unroll
    for (int i = 0; i < 4; ++i) {
        const float4* xp4 = (const float4*)(x + (size_t)(p0 + i) * PLANE);
        for (int j = t; j < PLANE4; j += 256) {
            float4 v = xp4[j];
            int h = j / 14, w4 = (j - h * 14) * 4;
            float h0 = cH0[i][h], h1 = cH1[i][h];
            acc[i] += v.x * (h0 * cW0[i][w4]     + h1 * cW1[i][w4]);
            acc[i] += v.y * (h0 * cW0[i][w4 + 1] + h1 * cW1[i][w4 + 1]);
            acc[i] += v.z * (h0 * cW0[i][w4 + 2] + h1 * cW1[i][w4 + 2]);
            acc[i] += v.w * (h0 * cW0[i][w4 + 3] + h1 * cW1[i][w4 + 3]);
        }
    }
    int w = t >> 6, lane = t & 63;
    #pragma unroll
    for (int i = 0; i < 4; ++i) {
        float s = wave_sum(acc[i]);
        if (lane == 0) part[i][w] = s;
    }
    __syncthreads();
    if (t < 4)
        tvec[p0 + t] = (part[t][0] + part[t][1] + part[t][2] + part[t][3]) * (1.f / PLANE);
}

__global__ __launch_bounds__(256) void k_final(const float* __restrict__ x,
        const float* __restrict__ y, const float* __restrict__ g,
        const float* __restrict__ wh, const float* __restrict__ bh,
        const float* __restrict__ ww, const float* __restrict__ bw,
        const float* __restrict__ tvec,
        const float* __restrict__ cw1, const float* __restrict__ cw2,
        const float* __restrict__ cb2, float* __restrict__ out) {
    int t = threadIdx.x;
    int p0 = blockIdx.x * 4;
    int n = p0 >> 8, c0 = p0 & 255;
    __shared__ float ybuf[YN];
    __shared__ float cH0[4][CL], cW0[4][CL], cH1[4][CL], cW1[4][CL];
    __shared__ float hid[64];
    __shared__ float sS[4];
    for (int i = t; i < YN; i += 256) ybuf[i] = y[(size_t)n * YN + i];
    if (t >= 192) {
        int j = t - 192;
        float acc = 0.f;
        for (int c = 0; c < CB; ++c) acc += tvec[n * CB + c] * cw1[j * CB + c];
        hid[j] = fmaxf(acc, 0.f);
    }
    __syncthreads();
    if (t < 4) {
        int c = c0 + t;
        float acc = cb2[c];
        #pragma unroll 8
        for (int j = 0; j < 64; ++j) acc += hid[j] * cw2[c * 64 + j];
        sS[t] = 1.f / (1.f + __expf(-acc));
    }
    build_coeffs_old(ybuf, wh, bh, ww, bw, g[n * 2], g[n * 2 + 1], c0, t, cH0, cW0, cH1, cW1);
    __syncthreads();
    #pragma unroll
    for (int i = 0; i < 4; ++i) {
        float sv = sS[i];
        const float4* xp4 = (const float4*)(x + (size_t)(p0 + i) * PLANE);
        float4* op4 = (float4*)(out + (size_t)(p0 + i) * PLANE);
        for (int j = t; j < PLANE4; j += 256) {
            float4 v = xp4[j];
            int h = j / 14, w4 = (j - h * 14) * 4;
            float h0 = cH0[i][h] * sv, h1 = cH1[i][h] * sv;
            float4 r;
            r.x = v.x * (h0 * cW0[i][w4]     + h1 * cW1[i][w4]     + 1.f);
            r.y = v.y * (h0 * cW0[i][w4 + 1] + h1 * cW1[i][w4 + 1] + 1.f);
            r.z = v.z * (h0 * cW0[i][w4 + 2] + h1 * cW1[i][w4 + 2] + 1.f);
            r.w = v.w * (h0 * cW0[i][w4 + 3] + h1 * cW1[i][w4 + 3] + 1.f);
            op4[j] = r;
        }
    }
}

extern "C" void kernel_launch(void* const* d_in, const int* in_sizes, int n_in,
                              void* d_out, int out_size, void* d_ws, size_t ws_size,
                              hipStream_t stream) {
    const float* x     = (const float*)d_in[0];
    const float* w1    = (const float*)d_in[1];
    const float* b1    = (const float*)d_in[2];
    const float* gamma = (const float*)d_in[3];
    const float* beta  = (const float*)d_in[4];
    const float* rmean = (const float*)d_in[5];
    const float* rvar  = (const float*)d_in[6];
    const float* wh    = (const float*)d_in[7];
    const float* bh    = (const float*)d_in[8];
    const float* ww    = (const float*)d_in[9];
    const float* bw    = (const float*)d_in[10];
    const float* gw1   = (const float*)d_in[11];
    const float* gw2   = (const float*)d_in[12];
    const float* gb2   = (const float*)d_in[13];
    const float* cw1   = (const float*)d_in[14];
    const float* cw2   = (const float*)d_in[15];
    const float* cb2   = (const float*)d_in[16];
    float* out = (float*)d_out;

    float* w = (float*)d_ws;
    float* ph   = w;
    float* pw   = ph + POOLSZ;
    float* mh   = pw + POOLSZ;
    float* mw   = mh + POOLSZ;
    float* ybuf = mw + POOLSZ;          // NB * YN
    float* gap  = ybuf + NB * YN;       // NB*CB
    float* tvec = gap + NB * CB;        // NB*CB
    float* gbuf = tvec + NB * CB;       // NB*2
    float* sbuf = gbuf + 64;            // NB*CB

    // Decide cooperative grid once (pure host-side query; capture-safe).
    static int g_grid = 0;              // >0: cooperative grid size, -1: fallback
    if (g_grid == 0) {
        int nb = 0;
        hipError_t qe = hipOccupancyMaxActiveBlocksPerMultiprocessor(
                &nb, (const void*)k_fused, 256, 0);
        if (qe != hipSuccess || nb < 1) {
            g_grid = -1;
        } else {
            long gg = (long)nb * NUM_CU;
            if (gg > NCHUNK) gg = NCHUNK;
            g_grid = (int)gg;
        }
    }

    bool coop_done = false;
    if (g_grid > 0) {
        KParams kp;
        kp.x = x; kp.w1 = w1; kp.b1 = b1; kp.gamma = gamma; kp.beta = beta;
        kp.rmean = rmean; kp.rvar = rvar; kp.wh = wh; kp.bh = bh; kp.ww = ww;
        kp.bw = bw; kp.gw1 = gw1; kp.gw2 = gw2; kp.gb2 = gb2; kp.cw1 = cw1;
        kp.cw2 = cw2; kp.cb2 = cb2;
        kp.ph = ph; kp.pw = pw; kp.mh = mh; kp.mw = mw; kp.gap = gap;
        kp.ybuf = ybuf; kp.gbuf = gbuf; kp.tvec = tvec; kp.sbuf = sbuf; kp.out = out;
        void* args[] = { (void*)&kp };
        hipError_t e = hipLaunchCooperativeKernel((const void*)k_fused,
                dim3(g_grid), dim3(256), args, 0, stream);
        if (e == hipSuccess) {
            coop_done = true;
        } else {
            (void)hipGetLastError();    // clear sticky error, use fallback path
            g_grid = -1;
        }
    }

    if (!coop_done) {
        k_pool<<<2048, 256, 0, stream>>>(x, ph, pw, mh, mw, gap);
        k_branch<<<dim3(NB, 2), 256, 0, stream>>>(ph, pw, mh, mw, gap,
                                                  w1, b1, gamma, beta, rmean, rvar,
                                                  gw1, gw2, gb2, ybuf, gbuf);
        k_tsum<<<2048, 256, 0, stream>>>(x, ybuf, gbuf, wh, bh, ww, bw, tvec);
        k_final<<<2048, 256, 0, stream>>>(x, ybuf, gbuf, wh, bh, ww, bw,
                                          tvec, cw1, cw2, cb2, out);
    }
}

// Round 2
// 284.691 us; speedup vs baseline: 1.8679x; 1.8679x over previous
//
#include <hip/hip_runtime.h>
#include <math.h>

#define NB 32
#define CB 256
#define HB 56
#define WB 56
#define PLANE 3136           // floats per (n,c) plane
#define PLANE4 784           // float4 per plane
#define CL 56
#define POOLSZ (NB*CB*CL)
#define YN 1792              // y floats per n: [br][m][l]
#define NCHUNK 1024          // 8-plane chunks
#define TBLN 1792            // table floats per chunk: cH0|cW0|cH1|cW1 (448 each)

__device__ inline float wave_sum(float v) {
    #pragma unroll
    for (int o = 32; o; o >>= 1) v += __shfl_xor(v, o, 64);
    return v;
}

// ---------------- Kernel 1: pooling. 4096 blocks x 256 thr, 2 planes, 1 sync ----
__global__ __launch_bounds__(256) void k_pool(const float* __restrict__ x,
        float* __restrict__ ph, float* __restrict__ pw,
        float* __restrict__ mh, float* __restrict__ mw, float* __restrict__ gap) {
    __shared__ float tile[2 * 3192];          // two 56x57 planes, 25.5 KB
    const int t = threadIdx.x, wv = t >> 6, ln = t & 63;
    const int pA = blockIdx.x * 2;
    const float4* x4 = (const float4*)(x + (size_t)pA * PLANE);
    for (int j = t; j < 2 * PLANE4; j += 256) {
        float4 v = x4[j];
        int pl = j >= PLANE4, jj = j - pl * PLANE4;
        int h = jj / 14, wq = jj - h * 14;
        float* d = &tile[pl * 3192 + h * 57 + wq * 4];
        d[0] = v.x; d[1] = v.y; d[2] = v.z; d[3] = v.w;
    }
    __syncthreads();
    const int pl = wv >> 1;                   // waves 0,1 -> plane A; 2,3 -> B
    const float* tb = &tile[pl * 3192];
    const size_t pidx = (size_t)(pA + pl) * CL;
    if (!(wv & 1)) {                          // even wave: column scans
        if (ln < CL) {
            float s = 0.f, m = -INFINITY;
            #pragma unroll 8
            for (int h = 0; h < HB; ++h) { float v = tb[h * 57 + ln]; s += v; m = fmaxf(m, v); }
            pw[pidx + ln] = s * (1.f / HB);
            mw[pidx + ln] = m;
        }
    } else {                                  // odd wave: row scans + gap
        float s = 0.f, m = -INFINITY;
        if (ln < CL) {
            #pragma unroll 8
            for (int wq = 0; wq < WB; ++wq) { float v = tb[ln * 57 + wq]; s += v; m = fmaxf(m, v); }
            ph[pidx + ln] = s * (1.f / WB);
            mh[pidx + ln] = m;
        }
        float tot = wave_sum(s);              // lanes >=56 contribute 0
        if (ln == 0) gap[pA + pl] = tot * (1.f / PLANE);
    }
}

// ---------------- Kernel 2: y activations + gate g. grid (32,2) x 256 -----------
// (verified round-0 version, unchanged)
__global__ __launch_bounds__(256) void k_branch(
        const float* __restrict__ ph, const float* __restrict__ pw,
        const float* __restrict__ mh, const float* __restrict__ mw,
        const float* __restrict__ gap,
        const float* __restrict__ w1, const float* __restrict__ b1,
        const float* __restrict__ gamma, const float* __restrict__ beta,
        const float* __restrict__ rmean, const float* __restrict__ rvar,
        const float* __restrict__ gw1, const float* __restrict__ gw2,
        const float* __restrict__ gb2,
        float* __restrict__ yout, float* __restrict__ g) {
    int n = blockIdx.x;
    int br = blockIdx.y;
    const float* pool_h = br ? mh : ph;
    const float* pool_w = br ? mw : pw;
    __shared__ float tile[CB * 113];
    __shared__ float lw1[8 * CB];
    __shared__ float hid[64];
    int t = threadIdx.x;

    for (int i = t; i < 8 * CB; i += 256) lw1[i] = w1[i];
    const float4* ph4 = (const float4*)(pool_h + (size_t)n * (CB * CL));
    const float4* pw4 = (const float4*)(pool_w + (size_t)n * (CB * CL));
    for (int j = t; j < 3584; j += 256) {
        int c = j / 14, w4 = (j - c * 14) * 4;
        float4 v = ph4[j];
        float* d = &tile[c * 113 + w4];
        d[0] = v.x; d[1] = v.y; d[2] = v.z; d[3] = v.w;
        v = pw4[j];
        d = &tile[c * 113 + 56 + w4];
        d[0] = v.x; d[1] = v.y; d[2] = v.z; d[3] = v.w;
    }
    __syncthreads();

    int grp = t / 112, l = t - grp * 112;
    if (grp < 2) {
        int m0 = grp * 4;
        float a0 = 0.f, a1 = 0.f, a2 = 0.f, a3 = 0.f;
        #pragma unroll 8
        for (int c = 0; c < CB; ++c) {
            float v = tile[c * 113 + l];
            a0 += v * lw1[(m0 + 0) * CB + c];
            a1 += v * lw1[(m0 + 1) * CB + c];
            a2 += v * lw1[(m0 + 2) * CB + c];
            a3 += v * lw1[(m0 + 3) * CB + c];
        }
        float acc[4] = {a0, a1, a2, a3};
        #pragma unroll
        for (int k = 0; k < 4; ++k) {
            int m = m0 + k;
            float scale = gamma[m] * rsqrtf(rvar[m] + 1e-5f);
            float val = (acc[k] + b1[m] - rmean[m]) * scale + beta[m];
            yout[(size_t)(n * 2 + br) * 896 + m * 112 + l] = fmaxf(val, 0.f);
        }
    }

    if (br == 0) {
        if (t >= 128 && t < 192) {
            int j = t - 128;
            float acc = 0.f;
            for (int c = 0; c < CB; ++c) acc += gap[n * CB + c] * gw1[j * CB + c];
            hid[j] = fmaxf(acc, 0.f);
        }
        __syncthreads();
        if (t == 0) {
            float l0 = gb2[0], l1 = gb2[1];
            for (int j = 0; j < 64; ++j) { l0 += hid[j] * gw2[j]; l1 += hid[j] * gw2[64 + j]; }
            float mx = fmaxf(l0, l1);
            float e0 = __expf(l0 - mx), e1 = __expf(l1 - mx);
            float inv = 1.f / (e0 + e1);
            g[n * 2]     = e0 * inv;
            g[n * 2 + 1] = e1 * inv;
        }
    }
}

// ---------------- Kernel 3: tables + tvec. 1024 blocks x 8 planes ---------------
__global__ __launch_bounds__(256) void k_tsum(const float* __restrict__ x,
        const float* __restrict__ y, const float* __restrict__ g,
        const float* __restrict__ wh, const float* __restrict__ bh,
        const float* __restrict__ ww, const float* __restrict__ bw,
        float* __restrict__ tvec, float* __restrict__ tbl) {
    __shared__ float smem[3616];              // yb[1792] | tables[1792] | part[32]
    const int t = threadIdx.x, wv = t >> 6, ln = t & 63;
    const int gq = blockIdx.x;
    const int q0 = gq * 8, qn = q0 >> 8, qc0 = q0 & 255;
    float* yb  = smem;
    float* cH0 = smem + 1792;
    float* cW0 = cH0 + 448;
    float* cH1 = cW0 + 448;
    float* cW1 = cH1 + 448;
    float* part = smem + 3584;

    for (int i = t; i < YN; i += 256) yb[i] = y[(size_t)qn * YN + i];
    __syncthreads();
    const float g0 = g[qn * 2], g1 = g[qn * 2 + 1];
    for (int task = t; task < 448; task += 256) {
        int ci = task / 56, l = task - ci * 56;
        int c = qc0 + ci;
        float h0 = bh[c], w0 = bw[c], h1 = h0, w1v = w0;
        #pragma unroll
        for (int m = 0; m < 8; ++m) {
            float whv = wh[c * 8 + m], wwv = ww[c * 8 + m];
            h0  += yb[m * 112 + l]            * whv;
            w0  += yb[m * 112 + 56 + l]       * wwv;
            h1  += yb[896 + m * 112 + l]      * whv;
            w1v += yb[896 + m * 112 + 56 + l] * wwv;
        }
        cH0[task] = 1.f / (1.f + __expf(-h0));
        cW0[task] = g0  / (1.f + __expf(-w0));
        cH1[task] = 1.f / (1.f + __expf(-h1));
        cW1[task] = g1  / (1.f + __expf(-w1v));
    }
    __syncthreads();

    // persist tables for k_final (coalesced float4 copy; overlaps with main loop)
    {
        const float4* ts = (const float4*)(cH0);
        float4* td = (float4*)(tbl + (size_t)gq * TBLN);
        for (int i = t; i < 448; i += 256) td[i] = ts[i];
    }

    #pragma unroll 1
    for (int i = 0; i < 8; ++i) {
        const float4* xp4 = (const float4*)(x + (size_t)(q0 + i) * PLANE);
        const float4* a4 = (const float4*)(cW0 + i * 56);
        const float4* b4 = (const float4*)(cW1 + i * 56);
        const float* h0p = cH0 + i * 56;
        const float* h1p = cH1 + i * 56;
        float acc = 0.f;
        for (int j = t; j < PLANE4; j += 256) {
            float4 v = xp4[j];
            int h = j / 14, wq = j - h * 14;
            float h0 = h0p[h], h1 = h1p[h];
            float4 a = a4[wq], b = b4[wq];
            acc += v.x * (h0 * a.x + h1 * b.x) + v.y * (h0 * a.y + h1 * b.y)
                 + v.z * (h0 * a.z + h1 * b.z) + v.w * (h0 * a.w + h1 * b.w);
        }
        float s = wave_sum(acc);
        if (ln == 0) part[i * 4 + wv] = s;
    }
    __syncthreads();
    if (t < 8)
        tvec[q0 + t] = (part[t * 4] + part[t * 4 + 1] + part[t * 4 + 2] + part[t * 4 + 3]) * (1.f / PLANE);
}

// ---------------- Kernel 4: final output. 1024 blocks x 8 planes ----------------
__global__ __launch_bounds__(256) void k_final(const float* __restrict__ x,
        const float* __restrict__ tbl, const float* __restrict__ tvec,
        const float* __restrict__ cw1, const float* __restrict__ cw2,
        const float* __restrict__ cb2, float* __restrict__ out) {
    __shared__ float smem[1792 + 256 + 64 + 8];   // tables | part_h[64][4] | hid | sS
    const int t = threadIdx.x;
    const int gq = blockIdx.x;
    const int q0 = gq * 8, qn = q0 >> 8, qc0 = q0 & 255;
    float* cH0 = smem;
    float* cW0 = cH0 + 448;
    float* cH1 = cW0 + 448;
    float* cW1 = cH1 + 448;
    float* part_h = smem + 1792;
    float* hid = smem + 2048;
    float* sS  = smem + 2112;

    // load precomputed tables (2 coalesced float4 iters)
    {
        const float4* ts = (const float4*)(tbl + (size_t)gq * TBLN);
        float4* td = (float4*)(smem);
        for (int i = t; i < 448; i += 256) td[i] = ts[i];
    }
    // s-gate hidden layer, parallel over all 256 threads (64 j x 4 c-chunks)
    {
        int j = t & 63, ch = t >> 6;
        const float* tv = tvec + qn * CB + ch * 64;
        const float* wp = cw1 + (size_t)j * CB + ch * 64;
        float acc = 0.f;
        #pragma unroll 8
        for (int c = 0; c < 64; ++c) acc += tv[c] * wp[c];
        part_h[j * 4 + ch] = acc;
    }
    __syncthreads();
    if (t < 64) {
        float4 p = *(const float4*)(part_h + t * 4);
        hid[t] = fmaxf(p.x + p.y + p.z + p.w, 0.f);
    }
    __syncthreads();
    if (t < 8) {                              // s for this chunk's 8 channels
        int c = qc0 + t;
        float acc = cb2[c];
        #pragma unroll 8
        for (int j = 0; j < 64; ++j) acc += hid[j] * cw2[c * 64 + j];
        sS[t] = 1.f / (1.f + __expf(-acc));
    }
    __syncthreads();

    #pragma unroll 1
    for (int i = 0; i < 8; ++i) {
        const float sv = sS[i];
        const float4* xp4 = (const float4*)(x + (size_t)(q0 + i) * PLANE);
        float4* op4 = (float4*)(out + (size_t)(q0 + i) * PLANE);
        const float4* a4 = (const float4*)(cW0 + i * 56);
        const float4* b4 = (const float4*)(cW1 + i * 56);
        const float* h0p = cH0 + i * 56;
        const float* h1p = cH1 + i * 56;
        for (int j = t; j < PLANE4; j += 256) {
            float4 v = xp4[j];
            int h = j / 14, wq = j - h * 14;
            float h0 = h0p[h] * sv, h1 = h1p[h] * sv;
            float4 a = a4[wq], b = b4[wq];
            float4 rr;
            rr.x = v.x * (h0 * a.x + h1 * b.x + 1.f);
            rr.y = v.y * (h0 * a.y + h1 * b.y + 1.f);
            rr.z = v.z * (h0 * a.z + h1 * b.z + 1.f);
            rr.w = v.w * (h0 * a.w + h1 * b.w + 1.f);
            op4[j] = rr;
        }
    }
}

extern "C" void kernel_launch(void* const* d_in, const int* in_sizes, int n_in,
                              void* d_out, int out_size, void* d_ws, size_t ws_size,
                              hipStream_t stream) {
    const float* x     = (const float*)d_in[0];
    const float* w1    = (const float*)d_in[1];
    const float* b1    = (const float*)d_in[2];
    const float* gamma = (const float*)d_in[3];
    const float* beta  = (const float*)d_in[4];
    const float* rmean = (const float*)d_in[5];
    const float* rvar  = (const float*)d_in[6];
    const float* wh    = (const float*)d_in[7];
    const float* bh    = (const float*)d_in[8];
    const float* ww    = (const float*)d_in[9];
    const float* bw    = (const float*)d_in[10];
    const float* gw1   = (const float*)d_in[11];
    const float* gw2   = (const float*)d_in[12];
    const float* gb2   = (const float*)d_in[13];
    const float* cw1   = (const float*)d_in[14];
    const float* cw2   = (const float*)d_in[15];
    const float* cb2   = (const float*)d_in[16];
    float* out = (float*)d_out;

    float* w = (float*)d_ws;
    float* ph   = w;
    float* pw   = ph + POOLSZ;
    float* mh   = pw + POOLSZ;
    float* mw   = mh + POOLSZ;
    float* ybuf = mw + POOLSZ;          // NB * YN
    float* gap  = ybuf + NB * YN;       // NB*CB
    float* tvec = gap + NB * CB;        // NB*CB
    float* gbuf = tvec + NB * CB;       // NB*2
    float* tbl  = gbuf + 64;            // NCHUNK * TBLN

    k_pool<<<4096, 256, 0, stream>>>(x, ph, pw, mh, mw, gap);
    k_branch<<<dim3(NB, 2), 256, 0, stream>>>(ph, pw, mh, mw, gap,
                                              w1, b1, gamma, beta, rmean, rvar,
                                              gw1, gw2, gb2, ybuf, gbuf);
    k_tsum<<<1024, 256, 0, stream>>>(x, ybuf, gbuf, wh, bh, ww, bw, tvec, tbl);
    k_final<<<1024, 256, 0, stream>>>(x, tbl, tvec, cw1, cw2, cb2, out);
}